// Round 1
// baseline (179.427 us; speedup 1.0000x reference)
//
#include <hip/hip_runtime.h>

// B=2,H=16,S=2048,D=64 attention, no 1/sqrt(d) scale, fp32 in/out.
// Round 10: kill redundant conversion VALU + exp mul.
//  - prep_kernel converts K->f16 / V->bf16^T ONCE into the exact swizzled
//    per-chunk LDS images (old code converted per consumer block = 32x
//    redundant, ~10% of attn VALU). Attn staging is now 4 raw uint4 loads +
//    4 ds_write_b128, no cvt, 16B-granule writes (LDS write phases halved).
//  - log2(e) folded into the Q fragment (f32 mul once/block) so exp(S) is a
//    bare v_exp_f32 (__builtin_amdgcn_exp2f): -32 v_mul per wave-iter.
//  - lp sums the unrounded f32 exp (drops 32 bf16->f32 cvt per wave-iter).
//  - s_setprio(1) around both MFMA clusters (T5; phase-diverse blocks).
//  - Workspace tiers: prep needs +16.8MB; if ws can't fit, falls back to the
//    proven R9 in-kernel fp32 staging path (template<PRE>).
// Carries from R9: 32-row waves x 4, 2-way key split + combine, S^T QK
// orientation, XOR-swizzled LDS, reg-prefetch pipeline, XCD head grouping.

typedef __bf16    bf16_t;
typedef _Float16  f16_t;
typedef __bf16    bf16x8 __attribute__((ext_vector_type(8)));
typedef _Float16  f16x8  __attribute__((ext_vector_type(8)));
typedef float     f32x4  __attribute__((ext_vector_type(4)));

constexpr int S  = 2048;
constexpr int Dh = 64;
constexpr int KT = 64;
constexpr int QT = 128;
constexpr float LOG2E = 1.44269504088896340736f;

// XOR swizzle on rows of 64 elems (2B each): 16B chunk idx ^= (row&7).
__device__ __forceinline__ int sw(int row, int col) {
    return row * 64 + ((((col >> 3) ^ (row & 7)) << 3) | (col & 7));
}

// ---- pre-pass: one (head,chunk) per block; emits the swizzled LDS images ----
// K image: f16,  elem idx = sw(key_in_chunk, d)
// V image: bf16, elem idx = sw(d, key_in_chunk)   (transposed)
__global__ __launch_bounds__(256)
void prep_kernel(const float* __restrict__ Kg, const float* __restrict__ Vg,
                 f16_t* __restrict__ Kpre, bf16_t* __restrict__ Vpre)
{
    const int tid = threadIdx.x;
    const int hc  = blockIdx.x;                    // head*32 + chunk (S=32*KT)
    const float* Kc = Kg + (size_t)hc * (KT * Dh); // chunks are contiguous
    const float* Vc = Vg + (size_t)hc * (KT * Dh);
    f16_t*  Ko = Kpre + (size_t)hc * (KT * Dh);
    bf16_t* Vo = Vpre + (size_t)hc * (KT * Dh);

    const int skey = tid >> 4;
    const int sc4  = (tid & 15) * 4;
    #pragma unroll
    for (int it = 0; it < 4; ++it) {
        const float4 k4 = *(const float4*)(Kc + (size_t)(it * 16 + skey) * Dh + sc4);
        const float xs[4] = {k4.x, k4.y, k4.z, k4.w};
        union { f16_t h[4]; uint2 u; } ph;
        #pragma unroll
        for (int j = 0; j < 4; ++j) ph.h[j] = (f16_t)xs[j];
        *(uint2*)&Ko[sw(it * 16 + skey, sc4)] = ph.u;
    }
    const int vkb = (tid >> 4) * 4;
    const int vc4 = (tid & 15) * 4;
    float4 vb4[4];
    #pragma unroll
    for (int i = 0; i < 4; ++i)
        vb4[i] = *(const float4*)(Vc + (size_t)(vkb + i) * Dh + vc4);
    const float rs[4][4] = {{vb4[0].x, vb4[1].x, vb4[2].x, vb4[3].x},
                            {vb4[0].y, vb4[1].y, vb4[2].y, vb4[3].y},
                            {vb4[0].z, vb4[1].z, vb4[2].z, vb4[3].z},
                            {vb4[0].w, vb4[1].w, vb4[2].w, vb4[3].w}};
    #pragma unroll
    for (int i = 0; i < 4; ++i) {
        union { bf16_t h[4]; uint2 u; } pv;
        #pragma unroll
        for (int j = 0; j < 4; ++j) pv.h[j] = (bf16_t)rs[i][j];
        *(uint2*)&Vo[sw(vc4 + i, vkb)] = pv.u;
    }
}

template<bool SPLIT, bool PRE>
__global__ __launch_bounds__(256, 4)
void attn_kernel(const float* __restrict__ Qg,
                 const void* __restrict__ Kin,
                 const void* __restrict__ Vin,
                 float* __restrict__ Og,
                 float* __restrict__ Opart,
                 float* __restrict__ lpart)
{
    __shared__ alignas(16) f16_t  Khs[KT * Dh];   // K   [key][d]  fp16 (8 KB)
    __shared__ alignas(16) bf16_t Vts[Dh * KT];   // V^T [d][key]  bf16 (8 KB)
    __shared__ alignas(16) bf16_t Pbs[QT * Dh];   // P   [row][key] bf16 (16 KB)

    const int tid  = threadIdx.x;
    const int lane = tid & 63;
    const int wv   = tid >> 6;       // wave 0..3
    const int l15  = lane & 15;
    const int qd   = lane >> 4;      // quad 0..3
    const int wb   = wv * 32;        // wave's 32-row base in the 128-row tile

    const int bx   = blockIdx.x;
    const int head = bx & 31;                    // XCD grouping
    const int r5   = bx >> 5;
    const int qt   = SPLIT ? (r5 >> 1) : r5;     // 0..15
    const int half = SPLIT ? (r5 & 1) : 0;
    const int tile = head * 16 + qt;             // flat output tile id
    const int ch0  = SPLIT ? half * 16 : 0;
    const int nch  = SPLIT ? 16 : 32;

    const float* Qp = Qg + (size_t)tile * QT * Dh;

    // staging address components (constant per thread)
    const int skey = tid >> 4;          // raw K staging: key row
    const int sc4  = (tid & 15) * 4;    // raw K staging: 4-elem col
    const int vkb  = (tid >> 4) * 4;    // raw V staging: 4 consecutive keys
    const int vc4  = (tid & 15) * 4;    // raw V staging: 4 consecutive d

    // ---- Q fragments (B-frag), 2 subtiles x 2 k-steps; log2(e) folded ----
    f16x8 qf[2][2];
    #pragma unroll
    for (int sub = 0; sub < 2; ++sub) {
        const float* qrow = Qp + (size_t)(wb + sub * 16 + l15) * Dh;
        #pragma unroll
        for (int ks = 0; ks < 2; ++ks) {
            const float* p = qrow + ks * 32 + qd * 8;
            const float4 a = *(const float4*)(p);
            const float4 b = *(const float4*)(p + 4);
            const float xs[8] = {a.x, a.y, a.z, a.w, b.x, b.y, b.z, b.w};
            #pragma unroll
            for (int j = 0; j < 8; ++j) qf[sub][ks][j] = (f16_t)(xs[j] * LOG2E);
        }
    }

    f32x4 oa[2][4];      // O acc: [subtile][4 d-tiles of 16]
    float lp[2];         // row-sum partial per subtile (lane's q-row = l15)
    #pragma unroll
    for (int s2 = 0; s2 < 2; ++s2) {
        lp[s2] = 0.f;
        #pragma unroll
        for (int t = 0; t < 4; ++t) oa[s2][t] = (f32x4){0.f, 0.f, 0.f, 0.f};
    }

    // ---- prefetch first chunk into registers ----
    uint4  pk[2], pv[2];                 // PRE path: raw image quads
    float4 kbuf[4], vbuf[4];             // raw path: fp32 staging
    if constexpr (PRE) {
        const uint4* Kc = (const uint4*)Kin + (size_t)(head * 32 + ch0) * 512;
        const uint4* Vc = (const uint4*)Vin + (size_t)(head * 32 + ch0) * 512;
        pk[0] = Kc[tid]; pk[1] = Kc[tid + 256];
        pv[0] = Vc[tid]; pv[1] = Vc[tid + 256];
    } else {
        const float* Kc = (const float*)Kin + (size_t)(head * 32 + ch0) * (KT * Dh);
        const float* Vc = (const float*)Vin + (size_t)(head * 32 + ch0) * (KT * Dh);
        #pragma unroll
        for (int it = 0; it < 4; ++it)
            kbuf[it] = *(const float4*)(Kc + (size_t)(it * 16 + skey) * Dh + sc4);
        #pragma unroll
        for (int i = 0; i < 4; ++i)
            vbuf[i] = *(const float4*)(Vc + (size_t)(vkb + i) * Dh + vc4);
    }

    #pragma unroll 1
    for (int ci = 0; ci < nch; ++ci) {
        __syncthreads();   // prior iter done reading Khs/Vts

        // ---- write staged registers -> LDS ----
        if constexpr (PRE) {
            ((uint4*)Khs)[tid] = pk[0]; ((uint4*)Khs)[tid + 256] = pk[1];
            ((uint4*)Vts)[tid] = pv[0]; ((uint4*)Vts)[tid + 256] = pv[1];
        } else {
            #pragma unroll
            for (int it = 0; it < 4; ++it) {
                const float xs[4] = {kbuf[it].x, kbuf[it].y, kbuf[it].z, kbuf[it].w};
                union { f16_t h[4]; uint2 u; } ph;
                #pragma unroll
                for (int j = 0; j < 4; ++j) ph.h[j] = (f16_t)xs[j];
                *(uint2*)&Khs[sw(it * 16 + skey, sc4)] = ph.u;
            }
            const float rs[4][4] = {{vbuf[0].x, vbuf[1].x, vbuf[2].x, vbuf[3].x},
                                    {vbuf[0].y, vbuf[1].y, vbuf[2].y, vbuf[3].y},
                                    {vbuf[0].z, vbuf[1].z, vbuf[2].z, vbuf[3].z},
                                    {vbuf[0].w, vbuf[1].w, vbuf[2].w, vbuf[3].w}};
            #pragma unroll
            for (int i = 0; i < 4; ++i) {
                union { bf16_t h[4]; uint2 u; } pvv;
                #pragma unroll
                for (int j = 0; j < 4; ++j) pvv.h[j] = (bf16_t)rs[i][j];
                *(uint2*)&Vts[sw(vc4 + i, vkb)] = pvv.u;
            }
        }
        __syncthreads();

        // ---- issue global loads for next chunk (consumed next iteration) ----
        if (ci + 1 < nch) {
            if constexpr (PRE) {
                const uint4* Kc = (const uint4*)Kin + (size_t)(head * 32 + ch0 + ci + 1) * 512;
                const uint4* Vc = (const uint4*)Vin + (size_t)(head * 32 + ch0 + ci + 1) * 512;
                pk[0] = Kc[tid]; pk[1] = Kc[tid + 256];
                pv[0] = Vc[tid]; pv[1] = Vc[tid + 256];
            } else {
                const float* Kc = (const float*)Kin + (size_t)(head * 32 + ch0 + ci + 1) * (KT * Dh);
                const float* Vc = (const float*)Vin + (size_t)(head * 32 + ch0 + ci + 1) * (KT * Dh);
                #pragma unroll
                for (int it = 0; it < 4; ++it)
                    kbuf[it] = *(const float4*)(Kc + (size_t)(it * 16 + skey) * Dh + sc4);
                #pragma unroll
                for (int i = 0; i < 4; ++i)
                    vbuf[i] = *(const float4*)(Vc + (size_t)(vkb + i) * Dh + vc4);
            }
        }

        // ---- QK^T (S^T orientation), nt-PAIRS to cap register use ----
        // A = K frag [m=key][k=d] (shared by both subtiles), B = qf.
        // C col = l15 = q-row (within subtile), C row r = key = nt*16+qd*4+r.
        #pragma unroll
        for (int np = 0; np < 2; ++np) {
            f32x4 st[2][2];   // [sub][nt within pair]
            #pragma unroll
            for (int s2 = 0; s2 < 2; ++s2)
                #pragma unroll
                for (int t = 0; t < 2; ++t) st[s2][t] = (f32x4){0.f, 0.f, 0.f, 0.f};
            __builtin_amdgcn_s_setprio(1);
            #pragma unroll
            for (int ks = 0; ks < 2; ++ks) {
                const int co = ks * 32 + qd * 8;
                const f16x8 ak0 = *(const f16x8*)&Khs[sw((np * 2 + 0) * 16 + l15, co)];
                const f16x8 ak1 = *(const f16x8*)&Khs[sw((np * 2 + 1) * 16 + l15, co)];
                #pragma unroll
                for (int s2 = 0; s2 < 2; ++s2) {
                    st[s2][0] = __builtin_amdgcn_mfma_f32_16x16x32_f16(ak0, qf[s2][ks], st[s2][0], 0, 0, 0);
                    st[s2][1] = __builtin_amdgcn_mfma_f32_16x16x32_f16(ak1, qf[s2][ks], st[s2][1], 0, 0, 0);
                }
            }
            __builtin_amdgcn_s_setprio(0);
            // p = 2^s (log2e folded into Q; |arg| < ~90, fp32-safe)
            #pragma unroll
            for (int s2 = 0; s2 < 2; ++s2) {
                #pragma unroll
                for (int t = 0; t < 2; ++t) {
                    union { bf16_t h[4]; uint2 u; } pb;
                    #pragma unroll
                    for (int r = 0; r < 4; ++r) {
                        const float e = __builtin_amdgcn_exp2f(st[s2][t][r]);
                        lp[s2] += e;
                        pb.h[r] = (bf16_t)e;
                    }
                    *(uint2*)&Pbs[sw(wb + s2 * 16 + l15, (np * 2 + t) * 16 + qd * 4)] = pb.u;
                }
            }
        }
        // no barrier: PV A-frags read only this wave's 32 rows (same-wave order)

        // ---- PV: O += P * V; vb shared across subtiles ----
        __builtin_amdgcn_s_setprio(1);
        #pragma unroll
        for (int ks = 0; ks < 2; ++ks) {
            const int co = ks * 32 + qd * 8;
            const bf16x8 pa0 = *(const bf16x8*)&Pbs[sw(wb + l15,      co)];
            const bf16x8 pa1 = *(const bf16x8*)&Pbs[sw(wb + 16 + l15, co)];
            #pragma unroll
            for (int dt = 0; dt < 4; ++dt) {
                const bf16x8 vb = *(const bf16x8*)&Vts[sw(dt * 16 + l15, co)];
                oa[0][dt] = __builtin_amdgcn_mfma_f32_16x16x32_bf16(pa0, vb, oa[0][dt], 0, 0, 0);
                oa[1][dt] = __builtin_amdgcn_mfma_f32_16x16x32_bf16(pa1, vb, oa[1][dt], 0, 0, 0);
            }
        }
        __builtin_amdgcn_s_setprio(0);
    }

    // ---- reduce row sums (lane's lp covers q-row=l15; reduce across quads) ----
    #pragma unroll
    for (int s2 = 0; s2 < 2; ++s2) {
        lp[s2] += __shfl_xor(lp[s2], 16, 64);
        lp[s2] += __shfl_xor(lp[s2], 32, 64);
    }

    if (SPLIT) {
        float* Po = Opart + (size_t)(tile * 2 + half) * (QT * Dh);
        float* lq = lpart + (size_t)(tile * 2 + half) * QT;
        #pragma unroll
        for (int s2 = 0; s2 < 2; ++s2) {
            if (qd == 0) lq[wb + s2 * 16 + l15] = lp[s2];
            #pragma unroll
            for (int r = 0; r < 4; ++r) {
                const int row = wb + s2 * 16 + qd * 4 + r;
                #pragma unroll
                for (int dt = 0; dt < 4; ++dt)
                    Po[(size_t)row * Dh + dt * 16 + l15] = oa[s2][dt][r];
            }
        }
    } else {
        float* Op = Og + (size_t)tile * QT * Dh;
        #pragma unroll
        for (int s2 = 0; s2 < 2; ++s2) {
            #pragma unroll
            for (int r = 0; r < 4; ++r) {
                const float inv = 1.0f / __shfl(lp[s2], qd * 4 + r, 64);
                const int row = wb + s2 * 16 + qd * 4 + r;
                #pragma unroll
                for (int dt = 0; dt < 4; ++dt)
                    Op[(size_t)row * Dh + dt * 16 + l15] = oa[s2][dt][r] * inv;
            }
        }
    }
}

// O = (O0+O1)/(l0+l1); one thread per float4 of output.
__global__ __launch_bounds__(256)
void combine_kernel(const float* __restrict__ Opart,
                    const float* __restrict__ lpart,
                    float* __restrict__ Og)
{
    const int i  = blockIdx.x * 256 + threadIdx.x;   // float4 index
    const int q  = i >> 11;                          // tile 0..511 (2048 f4/tile)
    const int rw = (i >> 4) & 127;                   // row within tile
    const size_t e = (size_t)(i & 2047) * 4;
    const float4 a = *(const float4*)(Opart + (size_t)(2 * q)     * (QT * Dh) + e);
    const float4 b = *(const float4*)(Opart + (size_t)(2 * q + 1) * (QT * Dh) + e);
    const float  l = lpart[(size_t)(2 * q) * QT + rw] + lpart[(size_t)(2 * q + 1) * QT + rw];
    const float inv = 1.0f / l;
    float4 o;
    o.x = (a.x + b.x) * inv;
    o.y = (a.y + b.y) * inv;
    o.z = (a.z + b.z) * inv;
    o.w = (a.w + b.w) * inv;
    *(float4*)(Og + (size_t)i * 4) = o;
}

extern "C" void kernel_launch(void* const* d_in, const int* in_sizes, int n_in,
                              void* d_out, int out_size, void* d_ws, size_t ws_size,
                              hipStream_t stream)
{
    const float* Q = (const float*)d_in[0];
    const float* K = (const float*)d_in[1];
    const float* V = (const float*)d_in[2];
    float*       O = (float*)d_out;

    constexpr size_t NPART       = 1024;             // 512 tiles x 2 halves
    constexpr size_t OPART_ELEMS = NPART * QT * Dh;  // 8.39M floats
    constexpr size_t LPART_ELEMS = NPART * QT;
    constexpr size_t KVPRE_ELEMS = 32ull * S * Dh;   // 4.19M halfs per tensor
    constexpr size_t OP_BYTES    = OPART_ELEMS * sizeof(float);
    constexpr size_t LP_BYTES    = LPART_ELEMS * sizeof(float);
    constexpr size_t KV_BYTES    = 2 * KVPRE_ELEMS * 2;   // 16.78 MB

    const int n4 = (int)(OPART_ELEMS / 2 / 4);       // output float4 count

    if (ws_size >= OP_BYTES + LP_BYTES + KV_BYTES) {
        // tier 1: prep + split + combine
        float*  Opart = (float*)d_ws;
        float*  lpart = Opart + OPART_ELEMS;
        f16_t*  Kpre  = (f16_t*)(lpart + LPART_ELEMS);
        bf16_t* Vpre  = (bf16_t*)(Kpre + KVPRE_ELEMS);
        prep_kernel<<<dim3(1024), dim3(256), 0, stream>>>(K, V, Kpre, Vpre);
        attn_kernel<true, true><<<dim3(1024), dim3(256), 0, stream>>>(
            Q, Kpre, Vpre, nullptr, Opart, lpart);
        combine_kernel<<<dim3(n4 / 256), dim3(256), 0, stream>>>(Opart, lpart, O);
    } else if (ws_size >= OP_BYTES + LP_BYTES) {
        // tier 2: split + combine, in-kernel fp32 staging (R9 path)
        float* Opart = (float*)d_ws;
        float* lpart = Opart + OPART_ELEMS;
        attn_kernel<true, false><<<dim3(1024), dim3(256), 0, stream>>>(
            Q, K, V, nullptr, Opart, lpart);
        combine_kernel<<<dim3(n4 / 256), dim3(256), 0, stream>>>(Opart, lpart, O);
    } else if (ws_size >= KV_BYTES) {
        // tier 3: prep + non-split
        f16_t*  Kpre = (f16_t*)d_ws;
        bf16_t* Vpre = (bf16_t*)(Kpre + KVPRE_ELEMS);
        prep_kernel<<<dim3(1024), dim3(256), 0, stream>>>(K, V, Kpre, Vpre);
        attn_kernel<false, true><<<dim3(512), dim3(256), 0, stream>>>(
            Q, Kpre, Vpre, O, nullptr, nullptr);
    } else {
        // tier 4: no workspace at all
        attn_kernel<false, false><<<dim3(512), dim3(256), 0, stream>>>(
            Q, K, V, O, nullptr, nullptr);
    }
}

// Round 2
// 155.495 us; speedup vs baseline: 1.1539x; 1.1539x over previous
//
#include <hip/hip_runtime.h>

// B=2,H=16,S=2048,D=64 attention, no 1/sqrt(d) scale, fp32 in/out.
// Round 11: revert R10's prep pre-pass (cross-XCD placement caused +108MB
// HBM writes and +16us), keep its verified wins, fix V staging conflicts:
//  - V-transpose LDS writes were 8-way bank-conflicted in R9 (bulk of the
//    9.4M SQ_LDS_BANK_CONFLICT): per-instr key-chunk span was 2 -> 16 banks
//    for 128 dwords. Swapping the staging map (vkb=(tid&15)*4 keys,
//    vc4=(tid>>4)*4 d) makes chunk span 8 -> 32 banks = 4-phase floor.
//    Only the two constants change; downstream math is role-agnostic.
//  - log2(e) folded into Q fragment; exp(S) = bare v_exp_f32 (exp2).
//  - lp sums unrounded f32 exp (no bf16->f32 cvt).
//  - s_setprio(1) around both MFMA clusters.
// Carries from R9: 32-row waves x 4, 2-way key split + combine, S^T QK
// orientation, XOR-swizzled LDS, reg-prefetch pipeline, XCD head grouping.

typedef __bf16    bf16_t;
typedef _Float16  f16_t;
typedef __bf16    bf16x8 __attribute__((ext_vector_type(8)));
typedef _Float16  f16x8  __attribute__((ext_vector_type(8)));
typedef float     f32x4  __attribute__((ext_vector_type(4)));

constexpr int S  = 2048;
constexpr int Dh = 64;
constexpr int KT = 64;
constexpr int QT = 128;
constexpr float LOG2E = 1.44269504088896340736f;

// XOR swizzle on rows of 64 elems (2B each): 16B chunk idx ^= (row&7).
__device__ __forceinline__ int sw(int row, int col) {
    return row * 64 + ((((col >> 3) ^ (row & 7)) << 3) | (col & 7));
}

template<bool SPLIT>
__global__ __launch_bounds__(256, 4)
void attn_kernel(const float* __restrict__ Qg,
                 const float* __restrict__ Kg,
                 const float* __restrict__ Vg,
                 float* __restrict__ Og,
                 float* __restrict__ Opart,
                 float* __restrict__ lpart)
{
    __shared__ alignas(16) f16_t  Khs[KT * Dh];   // K   [key][d]  fp16 (8 KB)
    __shared__ alignas(16) bf16_t Vts[Dh * KT];   // V^T [d][key]  bf16 (8 KB)
    __shared__ alignas(16) bf16_t Pbs[QT * Dh];   // P   [row][key] bf16 (16 KB)

    const int tid  = threadIdx.x;
    const int lane = tid & 63;
    const int wv   = tid >> 6;       // wave 0..3
    const int l15  = lane & 15;
    const int qd   = lane >> 4;      // quad 0..3
    const int wb   = wv * 32;        // wave's 32-row base in the 128-row tile

    const int bx   = blockIdx.x;
    const int head = bx & 31;                    // XCD grouping
    const int r5   = bx >> 5;
    const int qt   = SPLIT ? (r5 >> 1) : r5;     // 0..15
    const int half = SPLIT ? (r5 & 1) : 0;
    const int tile = head * 16 + qt;             // flat output tile id
    const int ch0  = SPLIT ? half * 16 : 0;
    const int nch  = SPLIT ? 16 : 32;

    const float* Qp = Qg + (size_t)tile * QT * Dh;
    const float* Kp = Kg + (size_t)head * S * Dh;
    const float* Vp = Vg + (size_t)head * S * Dh;

    // staging address components (constant per thread)
    const int skey = tid >> 4;          // K staging: key row
    const int sc4  = (tid & 15) * 4;    // K staging: 4-elem col
    // V staging map SWAPPED vs R9: keys from tid&15, d from tid>>4.
    // Per-instr LDS write now spans 8 key-chunks (32 banks) instead of 2
    // (16 banks / 8-way conflict).
    const int vkb  = (tid & 15) * 4;    // V staging: 4 consecutive keys
    const int vc4  = (tid >> 4) * 4;    // V staging: 4 consecutive d

    // ---- Q fragments (B-frag), 2 subtiles x 2 k-steps; log2(e) folded ----
    f16x8 qf[2][2];
    #pragma unroll
    for (int sub = 0; sub < 2; ++sub) {
        const float* qrow = Qp + (size_t)(wb + sub * 16 + l15) * Dh;
        #pragma unroll
        for (int ks = 0; ks < 2; ++ks) {
            const float* p = qrow + ks * 32 + qd * 8;
            const float4 a = *(const float4*)(p);
            const float4 b = *(const float4*)(p + 4);
            const float xs[8] = {a.x, a.y, a.z, a.w, b.x, b.y, b.z, b.w};
            #pragma unroll
            for (int j = 0; j < 8; ++j) qf[sub][ks][j] = (f16_t)(xs[j] * LOG2E);
        }
    }

    f32x4 oa[2][4];      // O acc: [subtile][4 d-tiles of 16]
    float lp[2];         // row-sum partial per subtile (lane's q-row = l15)
    #pragma unroll
    for (int s2 = 0; s2 < 2; ++s2) {
        lp[s2] = 0.f;
        #pragma unroll
        for (int t = 0; t < 4; ++t) oa[s2][t] = (f32x4){0.f, 0.f, 0.f, 0.f};
    }

    // ---- prefetch first chunk into registers ----
    float4 kbuf[4], vbuf[4];
    {
        const float* Kc = Kp + (size_t)ch0 * KT * Dh;
        const float* Vc = Vp + (size_t)ch0 * KT * Dh;
        #pragma unroll
        for (int it = 0; it < 4; ++it)
            kbuf[it] = *(const float4*)(Kc + (size_t)(it * 16 + skey) * Dh + sc4);
        #pragma unroll
        for (int i = 0; i < 4; ++i)
            vbuf[i] = *(const float4*)(Vc + (size_t)(vkb + i) * Dh + vc4);
    }

    #pragma unroll 1
    for (int ci = 0; ci < nch; ++ci) {
        __syncthreads();   // prior iter done reading Khs/Vts

        // ---- write staged registers -> LDS (cvt off the load path) ----
        #pragma unroll
        for (int it = 0; it < 4; ++it) {
            const float xs[4] = {kbuf[it].x, kbuf[it].y, kbuf[it].z, kbuf[it].w};
            union { f16_t h[4]; uint2 u; } ph;
            #pragma unroll
            for (int j = 0; j < 4; ++j) ph.h[j] = (f16_t)xs[j];
            *(uint2*)&Khs[sw(it * 16 + skey, sc4)] = ph.u;
        }
        {
            const float rs[4][4] = {{vbuf[0].x, vbuf[1].x, vbuf[2].x, vbuf[3].x},
                                    {vbuf[0].y, vbuf[1].y, vbuf[2].y, vbuf[3].y},
                                    {vbuf[0].z, vbuf[1].z, vbuf[2].z, vbuf[3].z},
                                    {vbuf[0].w, vbuf[1].w, vbuf[2].w, vbuf[3].w}};
            #pragma unroll
            for (int i = 0; i < 4; ++i) {
                union { bf16_t h[4]; uint2 u; } pv;
                #pragma unroll
                for (int j = 0; j < 4; ++j) pv.h[j] = (bf16_t)rs[i][j];
                *(uint2*)&Vts[sw(vc4 + i, vkb)] = pv.u;
            }
        }
        __syncthreads();

        // ---- issue global loads for next chunk (consumed next iteration) ----
        if (ci + 1 < nch) {
            const float* Kc = Kp + (size_t)(ch0 + ci + 1) * KT * Dh;
            const float* Vc = Vp + (size_t)(ch0 + ci + 1) * KT * Dh;
            #pragma unroll
            for (int it = 0; it < 4; ++it)
                kbuf[it] = *(const float4*)(Kc + (size_t)(it * 16 + skey) * Dh + sc4);
            #pragma unroll
            for (int i = 0; i < 4; ++i)
                vbuf[i] = *(const float4*)(Vc + (size_t)(vkb + i) * Dh + vc4);
        }

        // ---- QK^T (S^T orientation), nt-PAIRS to cap register use ----
        // A = K frag [m=key][k=d] (shared by both subtiles), B = qf.
        // C col = l15 = q-row (within subtile), C row r = key = nt*16+qd*4+r.
        #pragma unroll
        for (int np = 0; np < 2; ++np) {
            f32x4 st[2][2];   // [sub][nt within pair]
            #pragma unroll
            for (int s2 = 0; s2 < 2; ++s2)
                #pragma unroll
                for (int t = 0; t < 2; ++t) st[s2][t] = (f32x4){0.f, 0.f, 0.f, 0.f};
            __builtin_amdgcn_s_setprio(1);
            #pragma unroll
            for (int ks = 0; ks < 2; ++ks) {
                const int co = ks * 32 + qd * 8;
                const f16x8 ak0 = *(const f16x8*)&Khs[sw((np * 2 + 0) * 16 + l15, co)];
                const f16x8 ak1 = *(const f16x8*)&Khs[sw((np * 2 + 1) * 16 + l15, co)];
                #pragma unroll
                for (int s2 = 0; s2 < 2; ++s2) {
                    st[s2][0] = __builtin_amdgcn_mfma_f32_16x16x32_f16(ak0, qf[s2][ks], st[s2][0], 0, 0, 0);
                    st[s2][1] = __builtin_amdgcn_mfma_f32_16x16x32_f16(ak1, qf[s2][ks], st[s2][1], 0, 0, 0);
                }
            }
            __builtin_amdgcn_s_setprio(0);
            // p = 2^s (log2e folded into Q; |arg| < ~90, fp32-safe)
            #pragma unroll
            for (int s2 = 0; s2 < 2; ++s2) {
                #pragma unroll
                for (int t = 0; t < 2; ++t) {
                    union { bf16_t h[4]; uint2 u; } pb;
                    #pragma unroll
                    for (int r = 0; r < 4; ++r) {
                        const float e = __builtin_amdgcn_exp2f(st[s2][t][r]);
                        lp[s2] += e;
                        pb.h[r] = (bf16_t)e;
                    }
                    *(uint2*)&Pbs[sw(wb + s2 * 16 + l15, (np * 2 + t) * 16 + qd * 4)] = pb.u;
                }
            }
        }
        // no barrier: PV A-frags read only this wave's 32 rows (same-wave order)

        // ---- PV: O += P * V; vb shared across subtiles ----
        __builtin_amdgcn_s_setprio(1);
        #pragma unroll
        for (int ks = 0; ks < 2; ++ks) {
            const int co = ks * 32 + qd * 8;
            const bf16x8 pa0 = *(const bf16x8*)&Pbs[sw(wb + l15,      co)];
            const bf16x8 pa1 = *(const bf16x8*)&Pbs[sw(wb + 16 + l15, co)];
            #pragma unroll
            for (int dt = 0; dt < 4; ++dt) {
                const bf16x8 vb = *(const bf16x8*)&Vts[sw(dt * 16 + l15, co)];
                oa[0][dt] = __builtin_amdgcn_mfma_f32_16x16x32_bf16(pa0, vb, oa[0][dt], 0, 0, 0);
                oa[1][dt] = __builtin_amdgcn_mfma_f32_16x16x32_bf16(pa1, vb, oa[1][dt], 0, 0, 0);
            }
        }
        __builtin_amdgcn_s_setprio(0);
    }

    // ---- reduce row sums (lane's lp covers q-row=l15; reduce across quads) ----
    #pragma unroll
    for (int s2 = 0; s2 < 2; ++s2) {
        lp[s2] += __shfl_xor(lp[s2], 16, 64);
        lp[s2] += __shfl_xor(lp[s2], 32, 64);
    }

    if (SPLIT) {
        float* Po = Opart + (size_t)(tile * 2 + half) * (QT * Dh);
        float* lq = lpart + (size_t)(tile * 2 + half) * QT;
        #pragma unroll
        for (int s2 = 0; s2 < 2; ++s2) {
            if (qd == 0) lq[wb + s2 * 16 + l15] = lp[s2];
            #pragma unroll
            for (int r = 0; r < 4; ++r) {
                const int row = wb + s2 * 16 + qd * 4 + r;
                #pragma unroll
                for (int dt = 0; dt < 4; ++dt)
                    Po[(size_t)row * Dh + dt * 16 + l15] = oa[s2][dt][r];
            }
        }
    } else {
        float* Op = Og + (size_t)tile * QT * Dh;
        #pragma unroll
        for (int s2 = 0; s2 < 2; ++s2) {
            #pragma unroll
            for (int r = 0; r < 4; ++r) {
                const float inv = 1.0f / __shfl(lp[s2], qd * 4 + r, 64);
                const int row = wb + s2 * 16 + qd * 4 + r;
                #pragma unroll
                for (int dt = 0; dt < 4; ++dt)
                    Op[(size_t)row * Dh + dt * 16 + l15] = oa[s2][dt][r] * inv;
            }
        }
    }
}

// O = (O0+O1)/(l0+l1); one thread per float4 of output.
__global__ __launch_bounds__(256)
void combine_kernel(const float* __restrict__ Opart,
                    const float* __restrict__ lpart,
                    float* __restrict__ Og)
{
    const int i  = blockIdx.x * 256 + threadIdx.x;   // float4 index
    const int q  = i >> 11;                          // tile 0..511 (2048 f4/tile)
    const int rw = (i >> 4) & 127;                   // row within tile
    const size_t e = (size_t)(i & 2047) * 4;
    const float4 a = *(const float4*)(Opart + (size_t)(2 * q)     * (QT * Dh) + e);
    const float4 b = *(const float4*)(Opart + (size_t)(2 * q + 1) * (QT * Dh) + e);
    const float  l = lpart[(size_t)(2 * q) * QT + rw] + lpart[(size_t)(2 * q + 1) * QT + rw];
    const float inv = 1.0f / l;
    float4 o;
    o.x = (a.x + b.x) * inv;
    o.y = (a.y + b.y) * inv;
    o.z = (a.z + b.z) * inv;
    o.w = (a.w + b.w) * inv;
    *(float4*)(Og + (size_t)i * 4) = o;
}

extern "C" void kernel_launch(void* const* d_in, const int* in_sizes, int n_in,
                              void* d_out, int out_size, void* d_ws, size_t ws_size,
                              hipStream_t stream)
{
    const float* Q = (const float*)d_in[0];
    const float* K = (const float*)d_in[1];
    const float* V = (const float*)d_in[2];
    float*       O = (float*)d_out;

    constexpr size_t NPART       = 1024;             // 512 tiles x 2 halves
    constexpr size_t OPART_ELEMS = NPART * QT * Dh;  // 8.39M floats
    constexpr size_t LPART_ELEMS = NPART * QT;
    constexpr size_t NEED = (OPART_ELEMS + LPART_ELEMS) * sizeof(float);

    if (ws_size >= NEED) {
        float* Opart = (float*)d_ws;
        float* lpart = Opart + OPART_ELEMS;
        attn_kernel<true><<<dim3(1024), dim3(256), 0, stream>>>(
            Q, K, V, nullptr, Opart, lpart);
        const int n4 = (int)(OPART_ELEMS / 2 / 4);   // output float4 count
        combine_kernel<<<dim3(n4 / 256), dim3(256), 0, stream>>>(Opart, lpart, O);
    } else {
        attn_kernel<false><<<dim3(512), dim3(256), 0, stream>>>(
            Q, K, V, O, nullptr, nullptr);
    }
}